// Round 11
// baseline (1304.114 us; speedup 1.0000x reference)
//
#include <hip/hip_runtime.h>
#include <cstddef>
#include <cstdint>

#define N_NODES 5120
#define E_EDGES 163840
#define F 256
#define TSTEPS 24
#define ND 1024          // GEMM N = 4*256 (gates, column-permuted)
#define XROWSTRIDE 6144  // T*F

typedef unsigned short u16;
typedef unsigned int u32;
typedef __bf16 bf16x8 __attribute__((ext_vector_type(8)));
typedef float f32x4 __attribute__((ext_vector_type(4)));

__device__ __forceinline__ u16 f2bf(float f) {
    u32 u = __float_as_uint(f);
    u = (u + 0x7FFFu + ((u >> 16) & 1u)) >> 16;  // round-to-nearest-even
    return (u16)u;
}
__device__ __forceinline__ float bf2f(u16 h) {
    return __uint_as_float((u32)h << 16);
}
__device__ __forceinline__ float fsigmoid(float x) {
    return 1.f / (1.f + __expf(-x));
}
__device__ __forceinline__ float ftanh(float x) {
    // tanh(x) = 1 - 2/(exp(2x)+1); saturates correctly for |x| large
    return 1.f - 2.f / (__expf(2.f * x) + 1.f);
}

// ---------------- graph preprocessing ----------------

__global__ void deg_kernel(const float* __restrict__ ew, const int* __restrict__ src,
                           float* __restrict__ deg) {
    int e = blockIdx.x * 256 + threadIdx.x;
    if (e < E_EDGES) atomicAdd(&deg[src[e]], ew[e]);
}

__global__ void dis_kernel(float* __restrict__ deg) {
    int n = blockIdx.x * 256 + threadIdx.x;
    if (n < N_NODES) {
        float d = deg[n];
        deg[n] = d > 0.f ? rsqrtf(d) : 0.f;
    }
}

__global__ void count_kernel(const int* __restrict__ dst, int* __restrict__ cnt) {
    int e = blockIdx.x * 256 + threadIdx.x;
    if (e < E_EDGES) atomicAdd(&cnt[dst[e]], 1);
}

// one block, 256 threads, 20 counts each (N_NODES = 256*20)
__global__ void scan_kernel(const int* __restrict__ cnt, int* __restrict__ row_ptr) {
    __shared__ int s[256];
    int tid = threadIdx.x;
    int base = tid * 20;
    int local[20];
    int sum = 0;
    #pragma unroll
    for (int i = 0; i < 20; i++) { local[i] = sum; sum += cnt[base + i]; }
    s[tid] = sum;
    __syncthreads();
    for (int off = 1; off < 256; off <<= 1) {
        int v = (tid >= off) ? s[tid - off] : 0;
        __syncthreads();
        s[tid] += v;
        __syncthreads();
    }
    int offset = (tid == 0) ? 0 : s[tid - 1];
    #pragma unroll
    for (int i = 0; i < 20; i++) row_ptr[base + i] = offset + local[i];
    if (tid == 0) row_ptr[N_NODES] = E_EDGES;
}

__global__ void fill_csr(const int* __restrict__ src, const int* __restrict__ dst,
                         const float* __restrict__ ew, const float* __restrict__ dis,
                         const int* __restrict__ row_ptr, int* __restrict__ cursor,
                         int* __restrict__ csr_src, float* __restrict__ csr_w) {
    int e = blockIdx.x * 256 + threadIdx.x;
    if (e >= E_EDGES) return;
    int s = src[e], d = dst[e];
    int pos = row_ptr[d] + atomicAdd(&cursor[d], 1);
    csr_src[pos] = s;
    // w_hat = (2/lambda_max)*(-dis[src]*w*dis[dst]); lambda_max=2 -> factor 1
    csr_w[pos] = -dis[s] * ew[e] * dis[d];
}

// Column permutation: col'(g, j) = (j>>4)*64 + g*16 + (j&15).
// Inverse: g = (c>>4)&3, j = (c>>6)*16 + (c&15).
// WT[c'][k] (bf16, k contiguous) = Wcat[k][g*256+j]
__global__ void build_wcatT(const float* __restrict__ Ws, const float* __restrict__ thetas,
                            u16* __restrict__ WT) {
    int idx = blockIdx.x * 256 + threadIdx.x;
    if (idx >= 1024 * 1024) return;
    int c = idx >> 10, k = idx & 1023;
    int g = (c >> 4) & 3;
    int j = (c >> 6) * 16 + (c & 15);
    float v;
    if (k < 256) {
        v = Ws[(g * 256 + k) * 256 + j];
    } else {
        int kc = (k >> 8) - 1;  // 0..2
        int rr = k & 255;
        v = thetas[((g * 3 + kc) * 256 + rr) * 256 + j];
    }
    WT[idx] = f2bf(v);
}

// bsum[c'] = bs[g*256+j] + cbs[g*256+j] in permuted column order
__global__ void build_bsum(const float* __restrict__ bs, const float* __restrict__ cbs,
                           float* __restrict__ bsum) {
    int c = blockIdx.x * 256 + threadIdx.x;
    if (c >= 1024) return;
    int g = (c >> 4) & 3;
    int j = (c >> 6) * 16 + (c & 15);
    bsum[c] = bs[g * 256 + j] + cbs[g * 256 + j];
}

// ---------------- prop: wave-per-node edge gather ----------------
// Node mapping XCD-aligned with gemm readers: block bid -> panel p = bid%80,
// sub i = bid/80, nodes n = p*64 + i*4 + wid (writer XCD == gemm reader XCD).

__global__ __launch_bounds__(256) void prop_kernel(
        const u16* __restrict__ xin, const u16* __restrict__ sub, float scale,
        const int* __restrict__ row_ptr, const int* __restrict__ csr_src,
        const float* __restrict__ csr_w, u16* __restrict__ out_bf,
        const float* __restrict__ X, int t, u16* __restrict__ xt_out) {
    __shared__ int s_src[4][64];
    __shared__ float s_w[4][64];
    int wid = threadIdx.x >> 6, l = threadIdx.x & 63;
    int p = blockIdx.x % 80, ii = blockIdx.x / 80;
    int n = p * 64 + ii * 4 + wid;
    int start = row_ptr[n], end = row_ptr[n + 1];
    float acc0 = 0.f, acc1 = 0.f, acc2 = 0.f, acc3 = 0.f;
    int fb = l * 4;  // this lane's 4 features
    for (int base = start; base < end; base += 64) {
        int chunk = min(64, end - base);
        if (l < chunk) {
            s_src[wid][l] = csr_src[base + l];
            s_w[wid][l] = csr_w[base + l];
        }
        #pragma unroll 4
        for (int i = 0; i < chunk; i++) {
            int s = s_src[wid][i];
            float wt = s_w[wid][i];
            ushort4 hv = *(const ushort4*)(xin + (size_t)s * F + fb);
            acc0 += wt * bf2f(hv.x);
            acc1 += wt * bf2f(hv.y);
            acc2 += wt * bf2f(hv.z);
            acc3 += wt * bf2f(hv.w);
        }
    }
    size_t o = (size_t)n * F + fb;
    float r0 = scale * acc0, r1 = scale * acc1, r2 = scale * acc2, r3 = scale * acc3;
    if (sub) {
        ushort4 sv = *(const ushort4*)(sub + o);
        r0 -= bf2f(sv.x); r1 -= bf2f(sv.y); r2 -= bf2f(sv.z); r3 -= bf2f(sv.w);
    }
    ushort4 ov;
    ov.x = f2bf(r0); ov.y = f2bf(r1); ov.z = f2bf(r2); ov.w = f2bf(r3);
    *(ushort4*)(out_bf + o) = ov;
    if (xt_out) {
        float4 xv = *(const float4*)(X + (size_t)n * XROWSTRIDE + (size_t)t * F + fb);
        ushort4 xo;
        xo.x = f2bf(xv.x); xo.y = f2bf(xv.y); xo.z = f2bf(xv.z); xo.w = f2bf(xv.w);
        *(ushort4*)(xt_out + o) = xo;
    }
}

// ---------------- fused bf16 MFMA GEMM + LSTM epilogue ----------------
// Tile 64x128, GBK=64, grid 80x8 = 640 blocks. DEPTH-2 PREFETCH (T4, 3 LDS
// buffers, 72 KB): tile k's loads issue at iter k-2 -> ~2 iterations (~400-600
// cyc) of cover for the ~600-cyc L2 latency that depth-1 (R5/R8) couldn't hide.
// Per iter: stage(k+2) -> s_waitcnt vmcnt(12) (retire tile-k only; 12 newer
// loads stay in flight) -> barrier -> compute(k) -> barrier.
// A[5120,1024] = [Xt | Hb | Tx1 | Tx2] (bf16, row stride 256)
// WT = B^T in permuted column order (n-major, k-contig)
#define GBM 64
#define GBN 128
#define GBK 64
#define NKS 16  // 1024 / GBK

__global__ __launch_bounds__(256) void mfma_gemm(
        const u16* __restrict__ Xt, const u16* __restrict__ Hb,
        const u16* __restrict__ T1, const u16* __restrict__ T2,
        const u16* __restrict__ WT, const float* __restrict__ bsum,
        float* __restrict__ Cst, float* __restrict__ Hout, u16* __restrict__ HbNew,
        int writeH, int isFirst) {
    __shared__ alignas(16) u16 As[3][GBM * GBK];
    __shared__ alignas(16) u16 Bs[3][GBN * GBK];
    int tid = threadIdx.x;
    int w = tid >> 6, l = tid & 63;
    int m0 = blockIdx.x * GBM, n0 = blockIdx.y * GBN;
    int wm = (w >> 1) * 32, wn = (w & 1) * 64;   // wave sub-tile 32x64

    // staging: chunk c covers LDS rows [c*8, c*8+8); lane l -> row c*8 + l/8.
    // rule #21: linear LDS dest + inverse-swizzled SOURCE col + swizzled READ.
    int srow = l >> 3;                // row & 7
    int scol = 8 * ((l & 7) ^ srow);  // source elem col for this lane's 16B

    f32x4 acc[2][4] = {};

    auto stage = [&](int ks, int buf) {  // 6 loads per wave (2 A + 4 B)
        int k0 = ks * GBK;
        int seg = k0 >> 8;
        const u16* ab = (seg == 0) ? Xt : (seg == 1) ? Hb : (seg == 2) ? T1 : T2;
        ab += (k0 & 255);
        const u16* bb = WT + k0;
        u16* Asb = &As[buf][0];
        u16* Bsb = &Bs[buf][0];
        #pragma unroll
        for (int i = 0; i < 2; i++) {
            int c = i * 4 + w;
            int row = c * 8 + srow;
            __builtin_amdgcn_global_load_lds(
                (const __attribute__((address_space(1))) u32*)(ab + (size_t)(m0 + row) * F + scol),
                (__attribute__((address_space(3))) u32*)(Asb + c * 512), 16, 0, 0);
        }
        #pragma unroll
        for (int i = 0; i < 4; i++) {
            int c = i * 4 + w;
            int row = c * 8 + srow;
            __builtin_amdgcn_global_load_lds(
                (const __attribute__((address_space(1))) u32*)(bb + (size_t)(n0 + row) * 1024 + scol),
                (__attribute__((address_space(3))) u32*)(Bsb + c * 512), 16, 0, 0);
        }
    };

    stage(0, 0);
    stage(1, 1);   // 12 loads/wave in flight

    for (int ks = 0; ks < NKS; ks++) {
        if (ks + 2 < NKS) {
            stage(ks + 2, (ks + 2) % 3);                      // 18 in flight
            asm volatile("s_waitcnt vmcnt(12)" ::: "memory"); // retire tile-ks (6 oldest)
        } else if (ks + 2 == NKS) {                           // ks = 14
            asm volatile("s_waitcnt vmcnt(6)" ::: "memory");  // tiles 14 done, 15 pending
        } else {                                              // ks = 15
            asm volatile("s_waitcnt vmcnt(0)" ::: "memory");
        }
        // all waves' tile-ks LDS writes visible after this barrier
        __builtin_amdgcn_s_barrier();
        __builtin_amdgcn_sched_barrier(0);

        const u16* Asb = &As[ks % 3][0];
        const u16* Bsb = &Bs[ks % 3][0];
        #pragma unroll
        for (int kk = 0; kk < 2; kk++) {
            int kr = kk * 32 + (l >> 4) * 8;
            bf16x8 af[2], bfr[4];
            #pragma unroll
            for (int mf = 0; mf < 2; mf++) {
                int r = wm + mf * 16 + (l & 15);
                af[mf] = *(const bf16x8*)(Asb + r * GBK + (kr ^ ((r & 7) << 3)));
            }
            #pragma unroll
            for (int nf = 0; nf < 4; nf++) {
                int r = wn + nf * 16 + (l & 15);
                bfr[nf] = *(const bf16x8*)(Bsb + r * GBK + (kr ^ ((r & 7) << 3)));
            }
            #pragma unroll
            for (int mf = 0; mf < 2; mf++)
                #pragma unroll
                for (int nf = 0; nf < 4; nf++)
                    acc[mf][nf] = __builtin_amdgcn_mfma_f32_16x16x32_bf16(
                        af[mf], bfr[nf], acc[mf][nf], 0, 0, 0);
        }
        // all waves done reading buf ks%3 (overwritten at iter ks+1's stage(ks+3))
        __builtin_amdgcn_s_barrier();
    }

    // LSTM epilogue. C/D layout: col = lane&15, row = (lane>>4)*4 + reg.
    // nf = gate (I,F,T,O); feature j = group*16 + cc, group = n0/64 + (w&1).
    int cr = (l >> 4) * 4, cc = l & 15;
    int feat = ((n0 >> 6) + (w & 1)) * 16 + cc;
    float bI = bsum[n0 + wn + 0  + cc];
    float bF = bsum[n0 + wn + 16 + cc];
    float bT = bsum[n0 + wn + 32 + cc];
    float bO = bsum[n0 + wn + 48 + cc];
    #pragma unroll
    for (int mf = 0; mf < 2; mf++) {
        #pragma unroll
        for (int r = 0; r < 4; r++) {
            int row = m0 + wm + mf * 16 + cr + r;
            size_t o = (size_t)row * F + feat;
            float I  = fsigmoid(acc[mf][0][r] + bI);
            float Fg = fsigmoid(acc[mf][1][r] + bF);
            float Tc = ftanh(acc[mf][2][r] + bT);
            float O  = fsigmoid(acc[mf][3][r] + bO);
            float cprev = isFirst ? 0.f : Cst[o];   // t=0: C starts at zero (buffer poisoned)
            float c  = Fg * cprev + I * Tc;
            Cst[o] = c;
            float h = O * ftanh(c);
            if (writeH) Hout[o] = h;   // fp32 H only needed at the final step
            HbNew[o] = f2bf(h);
        }
    }
}

// ---------------- launch ----------------

extern "C" void kernel_launch(void* const* d_in, const int* in_sizes, int n_in,
                              void* d_out, int out_size, void* d_ws, size_t ws_size,
                              hipStream_t stream) {
    const float* X   = (const float*)d_in[0];
    const float* ew  = (const float*)d_in[1];
    const float* Ws  = (const float*)d_in[2];
    const float* bs  = (const float*)d_in[3];
    const float* th  = (const float*)d_in[4];
    const float* cbs = (const float*)d_in[5];
    const int*   ei  = (const int*)d_in[6];
    const int* src = ei;
    const int* dst = ei + E_EDGES;

    float* H = (float*)d_out;               // N*F
    float* C = H + (size_t)N_NODES * F;     // N*F

    char* w = (char*)d_ws;
    size_t off = 0;
    auto alloc = [&](size_t bytes) {
        void* p = w + off;
        off += (bytes + 255) & ~(size_t)255;
        return p;
    };
    float* deg     = (float*)alloc(N_NODES * 4);
    int*   cnt     = (int*)  alloc(N_NODES * 4);
    int*   cursor  = (int*)  alloc(N_NODES * 4);
    int*   row_ptr = (int*)  alloc((N_NODES + 1) * 4);
    int*   csr_src = (int*)  alloc(E_EDGES * 4);
    float* csr_w   = (float*)alloc(E_EDGES * 4);
    u16*   WT      = (u16*)  alloc((size_t)1024 * 1024 * 2);
    float* bsum    = (float*)alloc(1024 * 4);
    u16*   Xtbf    = (u16*)  alloc((size_t)N_NODES * F * 2);
    u16*   Hb0     = (u16*)  alloc((size_t)N_NODES * F * 2);
    u16*   Hb1     = (u16*)  alloc((size_t)N_NODES * F * 2);
    u16*   Tx1bf   = (u16*)  alloc((size_t)N_NODES * F * 2);
    u16*   Tx2bf   = (u16*)  alloc((size_t)N_NODES * F * 2);

    hipMemsetAsync(Hb0, 0, (size_t)N_NODES * F * 2, stream);
    hipMemsetAsync(deg, 0, N_NODES * 4, stream);
    hipMemsetAsync(cnt, 0, N_NODES * 4, stream);
    hipMemsetAsync(cursor, 0, N_NODES * 4, stream);

    int eb = E_EDGES / 256;
    deg_kernel<<<eb, 256, 0, stream>>>(ew, src, deg);
    dis_kernel<<<N_NODES / 256, 256, 0, stream>>>(deg);
    count_kernel<<<eb, 256, 0, stream>>>(dst, cnt);
    scan_kernel<<<1, 256, 0, stream>>>(cnt, row_ptr);
    fill_csr<<<eb, 256, 0, stream>>>(src, dst, ew, deg, row_ptr, cursor, csr_src, csr_w);
    build_wcatT<<<(1024 * 1024) / 256, 256, 0, stream>>>(Ws, th, WT);
    build_bsum<<<4, 256, 0, stream>>>(bs, cbs, bsum);

    dim3 ggrid(N_NODES / GBM, ND / GBN);   // 80 x 8 = 640 blocks
    for (int t = 0; t < TSTEPS; t++) {
        u16* Hrd = (t & 1) ? Hb1 : Hb0;
        u16* Hwr = (t & 1) ? Hb0 : Hb1;
        // Tx1 = L_hat @ H   (+ fused X_t -> bf16 conversion)
        prop_kernel<<<N_NODES / 4, 256, 0, stream>>>(Hrd, nullptr, 1.f, row_ptr, csr_src,
                                                     csr_w, Tx1bf, X, t, Xtbf);
        // Tx2 = 2 * (L_hat @ Tx1) - H
        prop_kernel<<<N_NODES / 4, 256, 0, stream>>>(Tx1bf, Hrd, 2.f, row_ptr, csr_src,
                                                     csr_w, Tx2bf, nullptr, 0, nullptr);
        // gates + LSTM pointwise fused
        mfma_gemm<<<ggrid, 256, 0, stream>>>(Xtbf, Hrd, Tx1bf, Tx2bf, WT, bsum, C, H, Hwr,
                                             t == TSTEPS - 1 ? 1 : 0, t == 0 ? 1 : 0);
    }
}

// Round 12
// 1121.119 us; speedup vs baseline: 1.1632x; 1.1632x over previous
//
#include <hip/hip_runtime.h>
#include <cstddef>
#include <cstdint>

#define N_NODES 5120
#define E_EDGES 163840
#define F 256
#define TSTEPS 24
#define ND 1024          // gate count = 4*256 (column-permuted)
#define XROWSTRIDE 6144  // T*F
#define MROWS (N_NODES * TSTEPS)   // 122880 rows of X viewed as [N*T][256]

typedef unsigned short u16;
typedef unsigned int u32;
typedef __bf16 bf16x8 __attribute__((ext_vector_type(8)));
typedef float f32x4 __attribute__((ext_vector_type(4)));

__device__ __forceinline__ u16 f2bf(float f) {
    u32 u = __float_as_uint(f);
    u = (u + 0x7FFFu + ((u >> 16) & 1u)) >> 16;  // round-to-nearest-even
    return (u16)u;
}
__device__ __forceinline__ float bf2f(u16 h) {
    return __uint_as_float((u32)h << 16);
}
__device__ __forceinline__ float fsigmoid(float x) {
    return 1.f / (1.f + __expf(-x));
}
__device__ __forceinline__ float ftanh(float x) {
    return 1.f - 2.f / (__expf(2.f * x) + 1.f);
}

// ---------------- graph preprocessing ----------------

__global__ void deg_kernel(const float* __restrict__ ew, const int* __restrict__ src,
                           float* __restrict__ deg) {
    int e = blockIdx.x * 256 + threadIdx.x;
    if (e < E_EDGES) atomicAdd(&deg[src[e]], ew[e]);
}

__global__ void dis_kernel(float* __restrict__ deg) {
    int n = blockIdx.x * 256 + threadIdx.x;
    if (n < N_NODES) {
        float d = deg[n];
        deg[n] = d > 0.f ? rsqrtf(d) : 0.f;
    }
}

__global__ void count_kernel(const int* __restrict__ dst, int* __restrict__ cnt) {
    int e = blockIdx.x * 256 + threadIdx.x;
    if (e < E_EDGES) atomicAdd(&cnt[dst[e]], 1);
}

// one block, 256 threads, 20 counts each (N_NODES = 256*20)
__global__ void scan_kernel(const int* __restrict__ cnt, int* __restrict__ row_ptr) {
    __shared__ int s[256];
    int tid = threadIdx.x;
    int base = tid * 20;
    int local[20];
    int sum = 0;
    #pragma unroll
    for (int i = 0; i < 20; i++) { local[i] = sum; sum += cnt[base + i]; }
    s[tid] = sum;
    __syncthreads();
    for (int off = 1; off < 256; off <<= 1) {
        int v = (tid >= off) ? s[tid - off] : 0;
        __syncthreads();
        s[tid] += v;
        __syncthreads();
    }
    int offset = (tid == 0) ? 0 : s[tid - 1];
    #pragma unroll
    for (int i = 0; i < 20; i++) row_ptr[base + i] = offset + local[i];
    if (tid == 0) row_ptr[N_NODES] = E_EDGES;
}

__global__ void fill_csr(const int* __restrict__ src, const int* __restrict__ dst,
                         const float* __restrict__ ew, const float* __restrict__ dis,
                         const int* __restrict__ row_ptr, int* __restrict__ cursor,
                         int* __restrict__ csr_src, float* __restrict__ csr_w) {
    int e = blockIdx.x * 256 + threadIdx.x;
    if (e >= E_EDGES) return;
    int s = src[e], d = dst[e];
    int pos = row_ptr[d] + atomicAdd(&cursor[d], 1);
    csr_src[pos] = s;
    // w_hat = (2/lambda_max)*(-dis[src]*w*dis[dst]); lambda_max=2 -> factor 1
    csr_w[pos] = -dis[s] * ew[e] * dis[d];
}

// Column permutation: col'(g, j) = (j>>4)*64 + g*16 + (j&15).
// Inverse: g = (c>>4)&3, j = (c>>6)*16 + (c&15).
// WT[c'][k] (bf16, k contiguous) = Wcat[k][g*256+j]
__global__ void build_wcatT(const float* __restrict__ Ws, const float* __restrict__ thetas,
                            u16* __restrict__ WT) {
    int idx = blockIdx.x * 256 + threadIdx.x;
    if (idx >= 1024 * 1024) return;
    int c = idx >> 10, k = idx & 1023;
    int g = (c >> 4) & 3;
    int j = (c >> 6) * 16 + (c & 15);
    float v;
    if (k < 256) {
        v = Ws[(g * 256 + k) * 256 + j];
    } else {
        int kc = (k >> 8) - 1;  // 0..2
        int rr = k & 255;
        v = thetas[((g * 3 + kc) * 256 + rr) * 256 + j];
    }
    WT[idx] = f2bf(v);
}

// bsum[c'] = bs[g*256+j] + cbs[g*256+j] in permuted column order
__global__ void build_bsum(const float* __restrict__ bs, const float* __restrict__ cbs,
                           float* __restrict__ bsum) {
    int c = blockIdx.x * 256 + threadIdx.x;
    if (c >= 1024) return;
    int g = (c >> 4) & 3;
    int j = (c >> 6) * 16 + (c & 15);
    bsum[c] = bs[g * 256 + j] + cbs[g * 256 + j];
}

// ---------------- one-shot: X fp32 -> bf16 ----------------
__global__ void conv_x(const float* __restrict__ X, u16* __restrict__ Xbf) {
    size_t i = (size_t)blockIdx.x * 256 + threadIdx.x;  // float4 index
    float4 v = ((const float4*)X)[i];
    ushort4 o;
    o.x = f2bf(v.x); o.y = f2bf(v.y); o.z = f2bf(v.z); o.w = f2bf(v.w);
    ((ushort4*)Xbf)[i] = o;
}

// ---------------- one-shot: XW[t][n][c'] = X @ W1 (K=256), bf16 out ----------------
// Xbf viewed as [122880][256], row r = n*24 + t. Tile 64x128, grid 1920x8.
#define GBM 64
#define GBN 128
#define GBK 64

__global__ __launch_bounds__(256) void xw_gemm(
        const u16* __restrict__ Xbf, const u16* __restrict__ WT,
        u16* __restrict__ XW) {
    __shared__ alignas(16) u16 As[GBM * GBK];
    __shared__ alignas(16) u16 Bs[GBN * GBK];
    int tid = threadIdx.x;
    int w = tid >> 6, l = tid & 63;
    int m0 = blockIdx.x * GBM, n0 = blockIdx.y * GBN;
    int wm = (w >> 1) * 32, wn = (w & 1) * 64;
    int srow = l >> 3;
    int scol = 8 * ((l & 7) ^ srow);

    f32x4 acc[2][4] = {};

    for (int k0 = 0; k0 < 256; k0 += GBK) {
        const u16* ab = Xbf + k0;
        const u16* bb = WT + k0;   // seg0 k-rows of WT
        #pragma unroll
        for (int i = 0; i < 2; i++) {
            int c = i * 4 + w;
            int row = c * 8 + srow;
            __builtin_amdgcn_global_load_lds(
                (const __attribute__((address_space(1))) u32*)(ab + (size_t)(m0 + row) * F + scol),
                (__attribute__((address_space(3))) u32*)(As + c * 512), 16, 0, 0);
        }
        #pragma unroll
        for (int i = 0; i < 4; i++) {
            int c = i * 4 + w;
            int row = c * 8 + srow;
            __builtin_amdgcn_global_load_lds(
                (const __attribute__((address_space(1))) u32*)(bb + (size_t)(n0 + row) * 1024 + scol),
                (__attribute__((address_space(3))) u32*)(Bs + c * 512), 16, 0, 0);
        }
        __syncthreads();
        #pragma unroll
        for (int kk = 0; kk < 2; kk++) {
            int kr = kk * 32 + (l >> 4) * 8;
            bf16x8 af[2], bfr[4];
            #pragma unroll
            for (int mf = 0; mf < 2; mf++) {
                int r = wm + mf * 16 + (l & 15);
                af[mf] = *(const bf16x8*)(As + r * GBK + (kr ^ ((r & 7) << 3)));
            }
            #pragma unroll
            for (int nf = 0; nf < 4; nf++) {
                int r = wn + nf * 16 + (l & 15);
                bfr[nf] = *(const bf16x8*)(Bs + r * GBK + (kr ^ ((r & 7) << 3)));
            }
            #pragma unroll
            for (int mf = 0; mf < 2; mf++)
                #pragma unroll
                for (int nf = 0; nf < 4; nf++)
                    acc[mf][nf] = __builtin_amdgcn_mfma_f32_16x16x32_bf16(
                        af[mf], bfr[nf], acc[mf][nf], 0, 0, 0);
        }
        __syncthreads();
    }

    // store: row r = n*24 + t -> XW[t*5120*1024 + n*1024 + col], bf16
    int cr = (l >> 4) * 4, cc = l & 15;
    #pragma unroll
    for (int mf = 0; mf < 2; mf++) {
        #pragma unroll
        for (int rg = 0; rg < 4; rg++) {
            int r = m0 + wm + mf * 16 + cr + rg;
            int n = r / 24;
            int t = r - n * 24;
            size_t base = (size_t)t * N_NODES * ND + (size_t)n * ND + n0 + wn + cc;
            #pragma unroll
            for (int nf = 0; nf < 4; nf++)
                XW[base + nf * 16] = f2bf(acc[mf][nf][rg]);
        }
    }
}

// ---------------- prop: wave-per-node edge gather (R4-proven) ----------------

__global__ __launch_bounds__(256) void prop_kernel(
        const u16* __restrict__ xin, const u16* __restrict__ sub, float scale,
        const int* __restrict__ row_ptr, const int* __restrict__ csr_src,
        const float* __restrict__ csr_w, u16* __restrict__ out_bf) {
    __shared__ int s_src[4][64];
    __shared__ float s_w[4][64];
    int wid = threadIdx.x >> 6, l = threadIdx.x & 63;
    int n = blockIdx.x * 4 + wid;
    int start = row_ptr[n], end = row_ptr[n + 1];
    float acc0 = 0.f, acc1 = 0.f, acc2 = 0.f, acc3 = 0.f;
    int fb = l * 4;
    for (int base = start; base < end; base += 64) {
        int chunk = min(64, end - base);
        if (l < chunk) {
            s_src[wid][l] = csr_src[base + l];
            s_w[wid][l] = csr_w[base + l];
        }
        #pragma unroll 4
        for (int i = 0; i < chunk; i++) {
            int s = s_src[wid][i];
            float wt = s_w[wid][i];
            ushort4 hv = *(const ushort4*)(xin + (size_t)s * F + fb);
            acc0 += wt * bf2f(hv.x);
            acc1 += wt * bf2f(hv.y);
            acc2 += wt * bf2f(hv.z);
            acc3 += wt * bf2f(hv.w);
        }
    }
    size_t o = (size_t)n * F + fb;
    float r0 = scale * acc0, r1 = scale * acc1, r2 = scale * acc2, r3 = scale * acc3;
    if (sub) {
        ushort4 sv = *(const ushort4*)(sub + o);
        r0 -= bf2f(sv.x); r1 -= bf2f(sv.y); r2 -= bf2f(sv.z); r3 -= bf2f(sv.w);
    }
    ushort4 ov;
    ov.x = f2bf(r0); ov.y = f2bf(r1); ov.z = f2bf(r2); ov.w = f2bf(r3);
    *(ushort4*)(out_bf + o) = ov;
}

// ---------------- fused bf16 MFMA GEMM (K=768) + XW add + LSTM epilogue ----------------
// Tile 64x128, grid 80x8 = 640 blocks, R4-proven single-buffered K-loop.
// A segs: [Hb | Tx1 | Tx2] (K=768, 12 K-steps). B = WT rows k=256..1023.
// Epilogue: gates = acc + XW[t] (precomputed X@W1, bf16) + bsum.
#define NKS 12  // 768 / GBK

__global__ __launch_bounds__(256) void mfma_gemm(
        const u16* __restrict__ Hb, const u16* __restrict__ T1,
        const u16* __restrict__ T2, const u16* __restrict__ WT,
        const u16* __restrict__ XWt, const float* __restrict__ bsum,
        float* __restrict__ Cst, float* __restrict__ Hout, u16* __restrict__ HbNew,
        int writeH, int isFirst) {
    __shared__ alignas(16) u16 As[GBM * GBK];
    __shared__ alignas(16) u16 Bs[GBN * GBK];
    int tid = threadIdx.x;
    int w = tid >> 6, l = tid & 63;
    int m0 = blockIdx.x * GBM, n0 = blockIdx.y * GBN;
    int wm = (w >> 1) * 32, wn = (w & 1) * 64;
    int srow = l >> 3;
    int scol = 8 * ((l & 7) ^ srow);

    f32x4 acc[2][4] = {};

    for (int k0 = 0; k0 < 768; k0 += GBK) {
        int seg = k0 >> 8;
        const u16* ab = (seg == 0) ? Hb : (seg == 1) ? T1 : T2;
        ab += (k0 & 255);
        const u16* bb = WT + 256 + k0;
        #pragma unroll
        for (int i = 0; i < 2; i++) {
            int c = i * 4 + w;
            int row = c * 8 + srow;
            __builtin_amdgcn_global_load_lds(
                (const __attribute__((address_space(1))) u32*)(ab + (size_t)(m0 + row) * F + scol),
                (__attribute__((address_space(3))) u32*)(As + c * 512), 16, 0, 0);
        }
        #pragma unroll
        for (int i = 0; i < 4; i++) {
            int c = i * 4 + w;
            int row = c * 8 + srow;
            __builtin_amdgcn_global_load_lds(
                (const __attribute__((address_space(1))) u32*)(bb + (size_t)(n0 + row) * 1024 + scol),
                (__attribute__((address_space(3))) u32*)(Bs + c * 512), 16, 0, 0);
        }
        __syncthreads();
        #pragma unroll
        for (int kk = 0; kk < 2; kk++) {
            int kr = kk * 32 + (l >> 4) * 8;
            bf16x8 af[2], bfr[4];
            #pragma unroll
            for (int mf = 0; mf < 2; mf++) {
                int r = wm + mf * 16 + (l & 15);
                af[mf] = *(const bf16x8*)(As + r * GBK + (kr ^ ((r & 7) << 3)));
            }
            #pragma unroll
            for (int nf = 0; nf < 4; nf++) {
                int r = wn + nf * 16 + (l & 15);
                bfr[nf] = *(const bf16x8*)(Bs + r * GBK + (kr ^ ((r & 7) << 3)));
            }
            #pragma unroll
            for (int mf = 0; mf < 2; mf++)
                #pragma unroll
                for (int nf = 0; nf < 4; nf++)
                    acc[mf][nf] = __builtin_amdgcn_mfma_f32_16x16x32_bf16(
                        af[mf], bfr[nf], acc[mf][nf], 0, 0, 0);
        }
        __syncthreads();
    }

    // LSTM epilogue. C/D layout: col = lane&15, row = (lane>>4)*4 + reg.
    // nf = gate (I,F,T,O); feature j = group*16 + cc, group = n0/64 + (w&1).
    int cr = (l >> 4) * 4, cc = l & 15;
    int feat = ((n0 >> 6) + (w & 1)) * 16 + cc;
    float bI = bsum[n0 + wn + 0  + cc];
    float bF = bsum[n0 + wn + 16 + cc];
    float bT = bsum[n0 + wn + 32 + cc];
    float bO = bsum[n0 + wn + 48 + cc];
    #pragma unroll
    for (int mf = 0; mf < 2; mf++) {
        #pragma unroll
        for (int r = 0; r < 4; r++) {
            int row = m0 + wm + mf * 16 + cr + r;
            size_t xb = (size_t)row * ND + n0 + wn + cc;
            float xI = bf2f(XWt[xb + 0]);
            float xF = bf2f(XWt[xb + 16]);
            float xT = bf2f(XWt[xb + 32]);
            float xO = bf2f(XWt[xb + 48]);
            size_t o = (size_t)row * F + feat;
            float I  = fsigmoid(acc[mf][0][r] + xI + bI);
            float Fg = fsigmoid(acc[mf][1][r] + xF + bF);
            float Tc = ftanh(acc[mf][2][r] + xT + bT);
            float O  = fsigmoid(acc[mf][3][r] + xO + bO);
            float cprev = isFirst ? 0.f : Cst[o];
            float c  = Fg * cprev + I * Tc;
            Cst[o] = c;
            float h = O * ftanh(c);
            if (writeH) Hout[o] = h;
            HbNew[o] = f2bf(h);
        }
    }
}

// ---------------- launch ----------------

extern "C" void kernel_launch(void* const* d_in, const int* in_sizes, int n_in,
                              void* d_out, int out_size, void* d_ws, size_t ws_size,
                              hipStream_t stream) {
    const float* X   = (const float*)d_in[0];
    const float* ew  = (const float*)d_in[1];
    const float* Ws  = (const float*)d_in[2];
    const float* bs  = (const float*)d_in[3];
    const float* th  = (const float*)d_in[4];
    const float* cbs = (const float*)d_in[5];
    const int*   ei  = (const int*)d_in[6];
    const int* src = ei;
    const int* dst = ei + E_EDGES;

    float* H = (float*)d_out;               // N*F
    float* C = H + (size_t)N_NODES * F;     // N*F

    char* w = (char*)d_ws;
    size_t off = 0;
    auto alloc = [&](size_t bytes) {
        void* p = w + off;
        off += (bytes + 255) & ~(size_t)255;
        return p;
    };
    float* deg     = (float*)alloc(N_NODES * 4);
    int*   cnt     = (int*)  alloc(N_NODES * 4);
    int*   cursor  = (int*)  alloc(N_NODES * 4);
    int*   row_ptr = (int*)  alloc((N_NODES + 1) * 4);
    int*   csr_src = (int*)  alloc(E_EDGES * 4);
    float* csr_w   = (float*)alloc(E_EDGES * 4);
    u16*   WT      = (u16*)  alloc((size_t)1024 * 1024 * 2);
    float* bsum    = (float*)alloc(1024 * 4);
    u16*   Hb0     = (u16*)  alloc((size_t)N_NODES * F * 2);
    u16*   Hb1     = (u16*)  alloc((size_t)N_NODES * F * 2);
    u16*   Tx1bf   = (u16*)  alloc((size_t)N_NODES * F * 2);
    u16*   Tx2bf   = (u16*)  alloc((size_t)N_NODES * F * 2);
    u16*   Xbf     = (u16*)  alloc((size_t)MROWS * F * 2);        // 63 MB
    u16*   XW      = (u16*)  alloc((size_t)TSTEPS * N_NODES * ND * 2);  // 252 MB

    hipMemsetAsync(Hb0, 0, (size_t)N_NODES * F * 2, stream);
    hipMemsetAsync(deg, 0, N_NODES * 4, stream);
    hipMemsetAsync(cnt, 0, N_NODES * 4, stream);
    hipMemsetAsync(cursor, 0, N_NODES * 4, stream);

    int eb = E_EDGES / 256;
    deg_kernel<<<eb, 256, 0, stream>>>(ew, src, deg);
    dis_kernel<<<N_NODES / 256, 256, 0, stream>>>(deg);
    count_kernel<<<eb, 256, 0, stream>>>(dst, cnt);
    scan_kernel<<<1, 256, 0, stream>>>(cnt, row_ptr);
    fill_csr<<<eb, 256, 0, stream>>>(src, dst, ew, deg, row_ptr, cursor, csr_src, csr_w);
    build_wcatT<<<(1024 * 1024) / 256, 256, 0, stream>>>(Ws, th, WT);
    build_bsum<<<4, 256, 0, stream>>>(bs, cbs, bsum);

    // one-shot: convert X to bf16, then XW = X @ W1 for all t
    conv_x<<<(MROWS * F / 4) / 256, 256, 0, stream>>>(X, Xbf);
    dim3 xwgrid(MROWS / GBM, ND / GBN);   // 1920 x 8
    xw_gemm<<<xwgrid, 256, 0, stream>>>(Xbf, WT, XW);

    dim3 ggrid(N_NODES / GBM, ND / GBN);   // 80 x 8 = 640 blocks
    for (int t = 0; t < TSTEPS; t++) {
        u16* Hrd = (t & 1) ? Hb1 : Hb0;
        u16* Hwr = (t & 1) ? Hb0 : Hb1;
        // Tx1 = L_hat @ H
        prop_kernel<<<N_NODES / 4, 256, 0, stream>>>(Hrd, nullptr, 1.f, row_ptr, csr_src,
                                                     csr_w, Tx1bf);
        // Tx2 = 2 * (L_hat @ Tx1) - H
        prop_kernel<<<N_NODES / 4, 256, 0, stream>>>(Tx1bf, Hrd, 2.f, row_ptr, csr_src,
                                                     csr_w, Tx2bf);
        // gates (K=768) + XW[t] + LSTM pointwise fused
        mfma_gemm<<<ggrid, 256, 0, stream>>>(Hrd, Tx1bf, Tx2bf, WT,
                                             XW + (size_t)t * N_NODES * ND, bsum,
                                             C, H, Hwr,
                                             t == TSTEPS - 1 ? 1 : 0, t == 0 ? 1 : 0);
    }
}